// Round 4
// baseline (3561.522 us; speedup 1.0000x reference)
//
#include <hip/hip_runtime.h>

typedef unsigned int uint;
typedef _Float16 f16;
typedef _Float16 f16x2 __attribute__((ext_vector_type(2)));
typedef _Float16 f16x8 __attribute__((ext_vector_type(8)));
typedef float f32x4 __attribute__((ext_vector_type(4)));

#define N_TYPES 10000
#define HID 256
#define G4 1024
#define BATCH 32
#define SEQ 1024

// ---------------- K1: path table: path[n][h] = sum_d cumw_d * emb[anc[n,d]][h]
__global__ void k_path(const int* __restrict__ anc, const float* __restrict__ weight,
                       const float* __restrict__ emb, int D, f16* __restrict__ path) {
  int n = blockIdx.x;
  int h = threadIdx.x;
  float acc = 0.f, cw = 1.f;
  for (int d = 0; d < D; ++d) {
    int a = anc[n * D + d];
    if (a < 0) break;
    acc += cw * emb[a * HID + h];
    cw *= weight[a];
  }
  path[n * HID + h] = (f16)acc;
}

// ---------------- K0: convert W_ih -> f16, W_hh -> transposed packed f16 pairs, bias = b_ih+b_hh
// whh_t layout: [128 kpair][1024 row] u32 (pair = f16 k, k+1 of row)
__global__ void k_conv(const float* __restrict__ wih, const float* __restrict__ whh,
                       const float* __restrict__ bih, const float* __restrict__ bhh,
                       f16* __restrict__ wih_h, uint* __restrict__ whh_t,
                       float* __restrict__ bias) {
  int i = blockIdx.x * 256 + threadIdx.x;   // 262144 threads
  wih_h[i] = (f16)wih[i];
  if (i < G4 * 128) {
    int row = i >> 7, p = i & 127;
    f16x2 v;
    v.x = (f16)whh[row * HID + 2 * p];
    v.y = (f16)whh[row * HID + 2 * p + 1];
    whh_t[p * G4 + row] = __builtin_bit_cast(uint, v);
  }
  if (i < G4) bias[i] = bih[i] + bhh[i];
}

// ---------------- K2: proj[n][r] = sum_k path[n][k]*W_ih[r][k] + bias[r]   (M=10000,N=1024,K=256)
#define BM 128
#define BN 128
#define BK 64
#define LPAD 72
__global__ __launch_bounds__(256) void k_gemm(const f16* __restrict__ A,
                                              const f16* __restrict__ Bw,
                                              const float* __restrict__ bias,
                                              f16* __restrict__ C) {
  __shared__ f16 sA[BM][LPAD];
  __shared__ f16 sB[BN][LPAD];
  int m0 = blockIdx.x * BM, n0 = blockIdx.y * BN;
  int tid = threadIdx.x;
  int wid = tid >> 6, lane = tid & 63;
  int wm = wid & 1, wn = wid >> 1;
  f32x4 acc[4][4] = {};
  for (int k0 = 0; k0 < 256; k0 += BK) {
    __syncthreads();
    int r = tid >> 3, kc = (tid & 7) * 8;
    for (int i = 0; i < 4; ++i) {
      int row = r + 32 * i;
      int gm = m0 + row;
      uint4 va = make_uint4(0u, 0u, 0u, 0u);
      if (gm < N_TYPES) va = *(const uint4*)&A[gm * 256 + k0 + kc];
      *(uint4*)&sA[row][kc] = va;
      uint4 vb = *(const uint4*)&Bw[(n0 + row) * 256 + k0 + kc];
      *(uint4*)&sB[row][kc] = vb;
    }
    __syncthreads();
#pragma unroll
    for (int ks = 0; ks < 2; ++ks) {
      f16x8 af[4], bf[4];
      int kk = ks * 32 + (lane >> 4) * 8;
#pragma unroll
      for (int mt = 0; mt < 4; ++mt)
        af[mt] = *(const f16x8*)&sA[wm * 64 + mt * 16 + (lane & 15)][kk];
#pragma unroll
      for (int nt = 0; nt < 4; ++nt)
        bf[nt] = *(const f16x8*)&sB[wn * 64 + nt * 16 + (lane & 15)][kk];
#pragma unroll
      for (int mt = 0; mt < 4; ++mt)
#pragma unroll
        for (int nt = 0; nt < 4; ++nt)
          acc[mt][nt] = __builtin_amdgcn_mfma_f32_16x16x32_f16(af[mt], bf[nt], acc[mt][nt], 0, 0, 0);
    }
  }
#pragma unroll
  for (int mt = 0; mt < 4; ++mt)
#pragma unroll
    for (int nt = 0; nt < 4; ++nt)
#pragma unroll
      for (int q = 0; q < 4; ++q) {
        int row = m0 + wm * 64 + mt * 16 + (lane >> 4) * 4 + q;
        int col = n0 + wn * 64 + nt * 16 + (lane & 15);
        if (row < N_TYPES) C[row * G4 + col] = (f16)(acc[mt][nt][q] + bias[col]);
      }
}

// ---------------- K3: LSTM recurrence, v3.
// 128 WGs of 256 threads: bid = q*32 + b. All 4 WGs of batch b share bid%8 -> same XCD.
// Thread t: gate chunk=t>>6, jloc=t&63, row = chunk*256 + q*64 + jloc; holds W_hh row
// as 128 packed-f16-pair u32 in VGPRs.
//
// R1-R3 lesson: launch_bounds min-waves is only a LOWER bound; the RA targets max
// occupancy and sinks/remats the 128 loop-invariant weight loads into the step loop
// (VGPR_Count=76, ~6400cy/step of serialized L2 reloads). Fixes:
//   (a) amdgpu_waves_per_eu(1,1): occupancy target pinned to 1 wave/EU -> 256-VGPR budget
//   (b) per-step zero-cost asm "+v" pins on every w[p] -> cannot be sunk/remat'd.
__device__ __forceinline__ float dot2(uint wp, uint hp, float acc) {
#if __has_builtin(__builtin_amdgcn_fdot2)
  return __builtin_amdgcn_fdot2(__builtin_bit_cast(f16x2, wp),
                                __builtin_bit_cast(f16x2, hp), acc, false);
#else
  f16x2 a = __builtin_bit_cast(f16x2, wp);
  f16x2 b = __builtin_bit_cast(f16x2, hp);
  return acc + (float)a.x * (float)b.x + (float)a.y * (float)b.y;
#endif
}

__device__ __forceinline__ float sigm(float v) { return 1.f / (1.f + __expf(-v)); }
__device__ __forceinline__ float tanh_(float v) { return 1.f - 2.f / (__expf(2.f * v) + 1.f); }

__global__ __launch_bounds__(256)
__attribute__((amdgpu_waves_per_eu(1, 1)))
void k_lstm(const int* __restrict__ evs,
            const f16* __restrict__ proj,
            const uint* __restrict__ whh_t,
            uint* hbuf,   // [32][2][128] u32: pair p of h, double-buffered by step parity
            uint* flags,  // [4][32][1024] u32
            float* __restrict__ out) {
  int bid = blockIdx.x;
  int b = bid & 31, q = bid >> 5;
  int t = threadIdx.x;
  int chunk = t >> 6;          // gate index, == wave id
  int jloc = t & 63;           // == lane
  int j = q * 64 + jloc;
  int row = chunk * 256 + j;

  __shared__ float gl[256];

  uint w[128];
#pragma unroll
  for (int p = 0; p < 128; ++p) w[p] = whh_t[p * G4 + row];

  uint* myh = hbuf + b * 256;
  uint* mf = flags + (q * 32 + b) * SEQ;
  const int* ev = evs + b * SEQ;
  const f16* projr = proj + row;

  float c = 0.f;

  for (int step = 0; step < SEQ; ++step) {
    // x gather for this step (independent of h; issues before the flag wait)
    int e = ev[step];
    float x = (float)projr[e * G4];

    // force all 128 weight values resident in VGPRs at loop top (zero instructions)
#pragma unroll
    for (int p = 0; p < 128; ++p) asm volatile("" : "+v"(w[p]));

    uint hpx = 0u, hpy = 0u;   // pairs 2*jloc and 2*jloc+1 of h_{step-1}
    if (step > 0) {
      if (t < 3) {
        int qp = (q + 1 + t) & 3;
        const uint* f = flags + (qp * 32 + b) * SEQ + (step - 1);
        while (__hip_atomic_load(f, __ATOMIC_RELAXED, __HIP_MEMORY_SCOPE_AGENT) == 0u) {}
        (void)__hip_atomic_load(f, __ATOMIC_ACQUIRE, __HIP_MEMORY_SCOPE_AGENT);
      }
      __syncthreads();                                   // [A]
      const uint* hb = myh + ((step - 1) & 1) * 128;
      uint2 hp = *(const uint2*)(hb + 2 * jloc);
      hpx = hp.x; hpy = hp.y;
    }

    // matvec: pre = sum_k W_hh[row][k] * h[k]
    // lane l holds pairs 2l (hpx) and 2l+1 (hpy); readlane -> SGPR -> v_dot2_f32_f16
    int h0 = (int)hpx, h1 = (int)hpy;
    float a0 = 0.f, a1 = 0.f, a2 = 0.f, a3 = 0.f;
#pragma unroll
    for (int i = 0; i < 64; i += 2) {
      a0 = dot2(w[2 * i + 0], (uint)__builtin_amdgcn_readlane(h0, i), a0);
      a1 = dot2(w[2 * i + 1], (uint)__builtin_amdgcn_readlane(h1, i), a1);
      a2 = dot2(w[2 * i + 2], (uint)__builtin_amdgcn_readlane(h0, i + 1), a2);
      a3 = dot2(w[2 * i + 3], (uint)__builtin_amdgcn_readlane(h1, i + 1), a3);
    }
    float pre = ((a0 + a1) + (a2 + a3)) + x;

    // exchange the 4 gate pre-activations for my jloc via LDS
    gl[t] = pre;
    __syncthreads();                                     // [B]
    float gi = gl[jloc];
    float gf = gl[64 + jloc];
    float gg = gl[128 + jloc];
    float go = gl[192 + jloc];
    float iv = sigm(gi), fv = sigm(gf), gv = tanh_(gg), ov = sigm(go);
    c = fv * c + iv * gv;               // replicated identically in all 4 chunks
    float hval = ov * tanh_(c);

    // publish h (chunk 0 / wave 0 only): output + packed pairs to global.
    // No barrier needed: the release store below drains wave 0's own vmcnt,
    // and wave 0 is the only wave that stores to myh.
    float hn = __shfl_down(hval, 1);
    if (chunk == 0) {
      out[(step * BATCH + b) * HID + j] = hval;
      if ((jloc & 1) == 0) {
        f16x2 pk; pk.x = (f16)hval; pk.y = (f16)hn;
        uint pku = __builtin_bit_cast(uint, pk);
        int p = q * 32 + (jloc >> 1);
        myh[(step & 1) * 128 + p] = pku;
      }
      if (t == 0) {
        __hip_atomic_store(mf + step, 1u, __ATOMIC_RELEASE, __HIP_MEMORY_SCOPE_AGENT);
      }
    }
  }
}

extern "C" void kernel_launch(void* const* d_in, const int* in_sizes, int n_in,
                              void* d_out, int out_size, void* d_ws, size_t ws_size,
                              hipStream_t stream) {
  (void)n_in; (void)out_size; (void)ws_size;
  const int* evs = (const int*)d_in[0];
  const int* anc = (const int*)d_in[1];
  const float* weight = (const float*)d_in[2];
  const float* emb = (const float*)d_in[3];
  const float* wih = (const float*)d_in[4];
  const float* whh = (const float*)d_in[5];
  const float* bih = (const float*)d_in[6];
  const float* bhh = (const float*)d_in[7];
  int D = in_sizes[1] / N_TYPES;

  char* ws = (char*)d_ws;
  f16* path = (f16*)(ws);                       // 10000*256*2 = 5,120,000 (dead after k_gemm)
  f16* wih_h = (f16*)(ws + 5242880);            // 524,288
  uint* whh_t = (uint*)(ws + 5767168);          // 524,288
  float* bias = (float*)(ws + 6291456);         // 4,096
  f16* proj = (f16*)(ws + 6295552);             // 10000*1024*2 = 20,480,000
  uint* hbuf = (uint*)(ws + 26775552);          // 32,768
  uint* flags = (uint*)(ws);                    // 524,288 -- overlaps path, zeroed AFTER k_gemm
  float* out = (float*)d_out;

  k_conv<<<1024, 256, 0, stream>>>(wih, whh, bih, bhh, wih_h, whh_t, bias);
  k_path<<<N_TYPES, 256, 0, stream>>>(anc, weight, emb, D, path);
  k_gemm<<<dim3(79, 8), 256, 0, stream>>>(path, wih_h, bias, proj);
  hipMemsetAsync(flags, 0, 4 * 32 * SEQ * 4, stream);
  k_lstm<<<128, 256, 0, stream>>>(evs, proj, whh_t, hbuf, flags, out);
}

// Round 5
// 1636.700 us; speedup vs baseline: 2.1760x; 2.1760x over previous
//
#include <hip/hip_runtime.h>

typedef unsigned int uint;
typedef unsigned long long u64;
typedef _Float16 f16;
typedef _Float16 f16x2 __attribute__((ext_vector_type(2)));
typedef _Float16 f16x8 __attribute__((ext_vector_type(8)));
typedef float f32x4 __attribute__((ext_vector_type(4)));

#define N_TYPES 10000
#define HID 256
#define G4 1024
#define BATCH 32
#define SEQ 1024

// ---------------- K1: path table: path[n][h] = sum_d cumw_d * emb[anc[n,d]][h]
__global__ void k_path(const int* __restrict__ anc, const float* __restrict__ weight,
                       const float* __restrict__ emb, int D, f16* __restrict__ path) {
  int n = blockIdx.x;
  int h = threadIdx.x;
  float acc = 0.f, cw = 1.f;
  for (int d = 0; d < D; ++d) {
    int a = anc[n * D + d];
    if (a < 0) break;
    acc += cw * emb[a * HID + h];
    cw *= weight[a];
  }
  path[n * HID + h] = (f16)acc;
}

// ---------------- K0: convert W_ih -> f16, W_hh -> transposed packed f16 pairs, bias = b_ih+b_hh
// whh_t layout: [128 kpair][1024 row] u32 (pair = f16 k, k+1 of row)
__global__ void k_conv(const float* __restrict__ wih, const float* __restrict__ whh,
                       const float* __restrict__ bih, const float* __restrict__ bhh,
                       f16* __restrict__ wih_h, uint* __restrict__ whh_t,
                       float* __restrict__ bias) {
  int i = blockIdx.x * 256 + threadIdx.x;   // 262144 threads
  wih_h[i] = (f16)wih[i];
  if (i < G4 * 128) {
    int row = i >> 7, p = i & 127;
    f16x2 v;
    v.x = (f16)whh[row * HID + 2 * p];
    v.y = (f16)whh[row * HID + 2 * p + 1];
    whh_t[p * G4 + row] = __builtin_bit_cast(uint, v);
  }
  if (i < G4) bias[i] = bih[i] + bhh[i];
}

// ---------------- K2: proj[n][r] = sum_k path[n][k]*W_ih[r][k] + bias[r]   (M=10000,N=1024,K=256)
#define BM 128
#define BN 128
#define BK 64
#define LPAD 72
__global__ __launch_bounds__(256) void k_gemm(const f16* __restrict__ A,
                                              const f16* __restrict__ Bw,
                                              const float* __restrict__ bias,
                                              f16* __restrict__ C) {
  __shared__ f16 sA[BM][LPAD];
  __shared__ f16 sB[BN][LPAD];
  int m0 = blockIdx.x * BM, n0 = blockIdx.y * BN;
  int tid = threadIdx.x;
  int wid = tid >> 6, lane = tid & 63;
  int wm = wid & 1, wn = wid >> 1;
  f32x4 acc[4][4] = {};
  for (int k0 = 0; k0 < 256; k0 += BK) {
    __syncthreads();
    int r = tid >> 3, kc = (tid & 7) * 8;
    for (int i = 0; i < 4; ++i) {
      int row = r + 32 * i;
      int gm = m0 + row;
      uint4 va = make_uint4(0u, 0u, 0u, 0u);
      if (gm < N_TYPES) va = *(const uint4*)&A[gm * 256 + k0 + kc];
      *(uint4*)&sA[row][kc] = va;
      uint4 vb = *(const uint4*)&Bw[(n0 + row) * 256 + k0 + kc];
      *(uint4*)&sB[row][kc] = vb;
    }
    __syncthreads();
#pragma unroll
    for (int ks = 0; ks < 2; ++ks) {
      f16x8 af[4], bf[4];
      int kk = ks * 32 + (lane >> 4) * 8;
#pragma unroll
      for (int mt = 0; mt < 4; ++mt)
        af[mt] = *(const f16x8*)&sA[wm * 64 + mt * 16 + (lane & 15)][kk];
#pragma unroll
      for (int nt = 0; nt < 4; ++nt)
        bf[nt] = *(const f16x8*)&sB[wn * 64 + nt * 16 + (lane & 15)][kk];
#pragma unroll
      for (int mt = 0; mt < 4; ++mt)
#pragma unroll
        for (int nt = 0; nt < 4; ++nt)
          acc[mt][nt] = __builtin_amdgcn_mfma_f32_16x16x32_f16(af[mt], bf[nt], acc[mt][nt], 0, 0, 0);
    }
  }
#pragma unroll
  for (int mt = 0; mt < 4; ++mt)
#pragma unroll
    for (int nt = 0; nt < 4; ++nt)
#pragma unroll
      for (int qq = 0; qq < 4; ++qq) {
        int row = m0 + wm * 64 + mt * 16 + (lane >> 4) * 4 + qq;
        int col = n0 + wn * 64 + nt * 16 + (lane & 15);
        if (row < N_TYPES) C[row * G4 + col] = (f16)(acc[mt][nt][qq] + bias[col]);
      }
}

// ---------------- K3: LSTM recurrence, v4.
// 256 WGs of 512 threads: bid = q*32 + b (q = eighth 0..7, b = batch). One WG per CU.
// WG owns dims [q*32, q*32+32) for all 4 gates = 128 gate-rows; each row k-split
// across 4 waves: wave v -> kq = v>>1 (k quarter, WAVE-UNIFORM), rid = (v&1)*64+lane.
// Per-thread weights: only w[32] packed f16-pair u32 (~60 VGPR total -> RA keeps them
// resident without any pressure games; R1-R4 lesson: w[128] is un-allocatable).
//
// Cross-WG h exchange: NO flags, NO acquire/release. Each h pair is a self-validating
// 64-bit word {lo: packed f16x2, hi: step-tag} written/read with RELAXED agent-scope
// atomics. Relaxed => no buffer_inv => the XCD L2 is never invalidated (the R1-R4
// per-step agent-ACQUIRE invalidated L2 every step, evicting weights/proj/scratch ->
// ~8000 cy/step of IF-cache refetches). Tag==step polling + parity double-buffer;
// single 64-bit atomic makes data+tag indivisible so no ordering is needed.
__device__ __forceinline__ float dot2(uint wp, uint hp, float acc) {
#if __has_builtin(__builtin_amdgcn_fdot2)
  return __builtin_amdgcn_fdot2(__builtin_bit_cast(f16x2, wp),
                                __builtin_bit_cast(f16x2, hp), acc, false);
#else
  f16x2 a = __builtin_bit_cast(f16x2, wp);
  f16x2 b = __builtin_bit_cast(f16x2, hp);
  return acc + (float)a.x * (float)b.x + (float)a.y * (float)b.y;
#endif
}

__device__ __forceinline__ float sigm(float v) { return 1.f / (1.f + __expf(-v)); }
__device__ __forceinline__ float tanh_(float v) { return 1.f - 2.f / (__expf(2.f * v) + 1.f); }

__global__ __launch_bounds__(512, 2)
void k_lstm(const int* __restrict__ evs,
            const f16* __restrict__ proj,
            const uint* __restrict__ whh_t,
            u64* hglob,                 // [32 batch][2 slot][128 pair] self-validating words
            float* __restrict__ out) {
  int bid = blockIdx.x;
  int b = bid & 31, q = bid >> 5;      // all 8 WGs of batch b: bid == b (mod 8) -> same XCD
  int t = threadIdx.x;
  int v = t >> 6, l = t & 63;
  int kq = v >> 1;                     // k-quarter, wave-uniform (readlane needs this)
  int rid = (v & 1) * 64 + l;          // local gate-row 0..127
  int rowg = (rid >> 5) * 256 + q * 32 + (rid & 31);   // global gate-row

  __shared__ float pl[512];
  __shared__ float rt[128];

  uint w[32];
#pragma unroll
  for (int i = 0; i < 32; ++i) w[i] = whh_t[(kq * 32 + i) * G4 + rowg];

  u64* hb = hglob + b * 256;           // [2][128]
  const int* ev = evs + b * SEQ;

  // reducer thread t<128 handles row rid=t; x = proj[e][rrow]
  int rrow = (t >> 5) * 256 + q * 32 + (t & 31);
  float x_cur = 0.f, x_nxt = 0.f;
  if (t < 128) x_cur = (float)proj[(long)ev[0] * G4 + rrow];

  float c = 0.f;

  for (int step = 0; step < SEQ; ++step) {
    // ---- gather h_{step-1}: only lanes 0..31 (they are the readlane sources)
    int h0 = 0;
    if (step > 0) {
      if (l < 32) {
        const u64* src = hb + ((step - 1) & 1) * 128 + kq * 32 + l;
        u64 val;
        do {
          val = __hip_atomic_load(src, __ATOMIC_RELAXED, __HIP_MEMORY_SCOPE_AGENT);
        } while ((uint)(val >> 32) != (uint)step);
        h0 = (int)(uint)val;
      }
    }

    // ---- partial dot over pairs [kq*32, kq*32+32)
    float a0 = 0.f, a1 = 0.f, a2 = 0.f, a3 = 0.f;
#pragma unroll
    for (int i = 0; i < 32; i += 4) {
      a0 = dot2(w[i + 0], (uint)__builtin_amdgcn_readlane(h0, i + 0), a0);
      a1 = dot2(w[i + 1], (uint)__builtin_amdgcn_readlane(h0, i + 1), a1);
      a2 = dot2(w[i + 2], (uint)__builtin_amdgcn_readlane(h0, i + 2), a2);
      a3 = dot2(w[i + 3], (uint)__builtin_amdgcn_readlane(h0, i + 3), a3);
    }
    pl[kq * 128 + rid] = (a0 + a1) + (a2 + a3);

    // prefetch next step's x while everyone converges (full step of latency cover)
    if (t < 128 && step + 1 < SEQ) x_nxt = (float)proj[(long)ev[step + 1] * G4 + rrow];

    __syncthreads();                                   // [1] partials visible
    if (t < 128) rt[t] = pl[t] + pl[128 + t] + pl[256 + t] + pl[384 + t] + x_cur;
    __syncthreads();                                   // [2] row sums visible

    if (t < 32) {
      float gi = rt[t], gf = rt[32 + t], gg = rt[64 + t], go = rt[96 + t];
      float iv = sigm(gi), fv = sigm(gf), gv = tanh_(gg), ov = sigm(go);
      c = fv * c + iv * gv;
      float hval = ov * tanh_(c);
      out[(step * BATCH + b) * HID + q * 32 + t] = hval;
      float hA = __shfl(hval, 2 * (t & 15));
      float hB = __shfl(hval, 2 * (t & 15) + 1);
      if (t < 16) {
        f16x2 pk; pk.x = (f16)hA; pk.y = (f16)hB;
        uint pku = __builtin_bit_cast(uint, pk);
        u64 val = (u64)pku | ((u64)(uint)(step + 1) << 32);
        __hip_atomic_store(hb + (step & 1) * 128 + q * 16 + t, val,
                           __ATOMIC_RELAXED, __HIP_MEMORY_SCOPE_AGENT);
      }
    }
    x_cur = x_nxt;
    // no third barrier: next-step pl/rt writes are gated by barrier [1] of step+1,
    // which every thread reaches only after this step's reads are done.
  }
}

extern "C" void kernel_launch(void* const* d_in, const int* in_sizes, int n_in,
                              void* d_out, int out_size, void* d_ws, size_t ws_size,
                              hipStream_t stream) {
  (void)n_in; (void)out_size; (void)ws_size;
  const int* evs = (const int*)d_in[0];
  const int* anc = (const int*)d_in[1];
  const float* weight = (const float*)d_in[2];
  const float* emb = (const float*)d_in[3];
  const float* wih = (const float*)d_in[4];
  const float* whh = (const float*)d_in[5];
  const float* bih = (const float*)d_in[6];
  const float* bhh = (const float*)d_in[7];
  int D = in_sizes[1] / N_TYPES;

  char* ws = (char*)d_ws;
  f16* path = (f16*)(ws);                       // 10000*256*2 = 5,120,000 (dead after k_gemm)
  f16* wih_h = (f16*)(ws + 5242880);            // 524,288
  uint* whh_t = (uint*)(ws + 5767168);          // 524,288
  float* bias = (float*)(ws + 6291456);         // 4,096
  f16* proj = (f16*)(ws + 6295552);             // 10000*1024*2 = 20,480,000
  u64* hglob = (u64*)(ws + 26775552);           // 32*2*128*8 = 65,536
  float* out = (float*)d_out;

  k_conv<<<1024, 256, 0, stream>>>(wih, whh, bih, bhh, wih_h, whh_t, bias);
  k_path<<<N_TYPES, 256, 0, stream>>>(anc, weight, emb, D, path);
  k_gemm<<<dim3(79, 8), 256, 0, stream>>>(path, wih_h, bias, proj);
  hipMemsetAsync(hglob, 0, 32 * 2 * 128 * 8, stream);   // zero tags (replay-safe)
  k_lstm<<<256, 512, 0, stream>>>(evs, proj, whh_t, hglob, out);
}